// Round 1
// baseline (1338.957 us; speedup 1.0000x reference)
//
#include <hip/hip_runtime.h>
#include <hip/hip_bf16.h>
#include <math.h>

#define BB 8
#define NN 2048
#define KK 10
#define EPSF 1e-5f
#define NEG_SLOPE 0.2f

// ---------------- xx[n] = sum_c x[n,c]^2 ----------------
__global__ void xx_kernel(const float* __restrict__ x, float* __restrict__ xx, int C) {
    int i = blockIdx.x * blockDim.x + threadIdx.x;
    if (i >= BB * NN) return;
    const float* row = x + (size_t)i * C;
    float s = 0.f;
    for (int c = 0; c < C; ++c) { float v = row[c]; s = fmaf(v, v, s); }
    xx[i] = s;
}

// ---------------- dist[b,i,j] = 2*dot(xi,xj) - xx[i] - xx[j] ----------------
// 64x64 tile, 4x4 per thread, k-chunk=16, k-major LDS for float4 reads.
__global__ __launch_bounds__(256) void dist_gemm_kernel(
    const float* __restrict__ x, const float* __restrict__ xx,
    float* __restrict__ dist, int C, int b0) {
    int bz = blockIdx.z, b = b0 + bz;
    int i0 = blockIdx.y << 6, j0 = blockIdx.x << 6;
    const float* xb = x + (size_t)b * NN * C;
    __shared__ float As[16][68], Bs[16][68];
    int tid = threadIdx.x;
    int tx = tid & 15, ty = tid >> 4;
    float acc[4][4] = {};
    for (int k0 = 0; k0 < C; k0 += 16) {
        #pragma unroll
        for (int l = tid; l < 1024; l += 256) {
            int r = l >> 4, c = l & 15;
            int kc = k0 + c;
            As[c][r] = (kc < C) ? xb[(size_t)(i0 + r) * C + kc] : 0.f;
            Bs[c][r] = (kc < C) ? xb[(size_t)(j0 + r) * C + kc] : 0.f;
        }
        __syncthreads();
        #pragma unroll
        for (int kk = 0; kk < 16; ++kk) {
            float4 a4 = *(const float4*)&As[kk][ty << 2];
            float4 b4 = *(const float4*)&Bs[kk][tx << 2];
            float a[4] = {a4.x, a4.y, a4.z, a4.w};
            float bv[4] = {b4.x, b4.y, b4.z, b4.w};
            #pragma unroll
            for (int u = 0; u < 4; ++u)
                #pragma unroll
                for (int v = 0; v < 4; ++v)
                    acc[u][v] = fmaf(a[u], bv[v], acc[u][v]);
        }
        __syncthreads();
    }
    const float* xxb = xx + (size_t)b * NN;
    float xi[4], xj[4];
    #pragma unroll
    for (int u = 0; u < 4; ++u) xi[u] = xxb[i0 + (ty << 2) + u];
    #pragma unroll
    for (int v = 0; v < 4; ++v) xj[v] = xxb[j0 + (tx << 2) + v];
    float* db = dist + (size_t)bz * NN * NN;
    #pragma unroll
    for (int u = 0; u < 4; ++u) {
        int i = i0 + (ty << 2) + u;
        float4 o;
        o.x = 2.f * acc[u][0] - xi[u] - xj[0];
        o.y = 2.f * acc[u][1] - xi[u] - xj[1];
        o.z = 2.f * acc[u][2] - xi[u] - xj[2];
        o.w = 2.f * acc[u][3] - xi[u] - xj[3];
        *(float4*)&db[(size_t)i * NN + j0 + (tx << 2)] = o;
    }
}

// ---------------- top-10 per row, jax.lax.top_k semantics ----------------
// one wave (64 threads) per row; 32 candidates per thread in regs.
// Round r selects the successor (in (v desc, j asc) total order) of round r-1's winner.
__global__ __launch_bounds__(64) void topk_kernel(
    const float* __restrict__ dist, int* __restrict__ idxout, int b0) {
    int i = blockIdx.x, bz = blockIdx.y, b = b0 + bz;
    const float* row = dist + ((size_t)bz * NN + i) * NN;
    int t = threadIdx.x;
    float v[32];
    #pragma unroll
    for (int q = 0; q < 32; ++q) v[q] = row[t + (q << 6)];
    int* out = idxout + ((size_t)b * NN + i) * KK;
    float pv = INFINITY; int pj = -1;
    for (int r = 0; r < KK; ++r) {
        float bv = -INFINITY; int bj = NN;
        #pragma unroll
        for (int q = 0; q < 32; ++q) {
            int j = t + (q << 6);
            float vv = v[q];
            bool elig = (vv < pv) || (vv == pv && j > pj);
            bool better = elig && (vv > bv || (vv == bv && j < bj));
            bv = better ? vv : bv;
            bj = better ? j : bj;
        }
        #pragma unroll
        for (int s = 32; s > 0; s >>= 1) {
            float ov = __shfl_xor(bv, s);
            int oj = __shfl_xor(bj, s);
            if (ov > bv || (ov == bv && oj < bj)) { bv = ov; bj = oj; }
        }
        if (t == 0) out[r] = bj;
        pv = bv; pj = bj;
    }
}

// ---------------- y = X*W1^T, z = X*W2^T (w = [W1 | W2], row o has 2C) ----------------
#define TNPTS 8
__global__ void yz_kernel(const float* __restrict__ x, const float* __restrict__ w,
                          float* __restrict__ y, float* __restrict__ z, int C, int co) {
    int o = threadIdx.x;
    int n0 = blockIdx.x * TNPTS;
    extern __shared__ float xs[];  // TNPTS * C
    for (int l = o; l < TNPTS * C; l += co) xs[l] = x[(size_t)n0 * C + l];
    __syncthreads();
    float ay[TNPTS] = {}, az[TNPTS] = {};
    const float* wy = w + (size_t)o * 2 * C;
    const float* wz = wy + C;
    for (int c = 0; c < C; ++c) {
        float a = wy[c], bq = wz[c];
        #pragma unroll
        for (int p = 0; p < TNPTS; ++p) {
            float xv = xs[p * C + c];
            ay[p] = fmaf(xv, a, ay[p]);
            az[p] = fmaf(xv, bq, az[p]);
        }
    }
    for (int p = 0; p < TNPTS; ++p) {
        y[(size_t)(n0 + p) * co + o] = ay[p];
        z[(size_t)(n0 + p) * co + o] = az[p];
    }
}

// ---------------- gather + max_k + BN + lrelu ----------------
__global__ void edge_apply_kernel(const float* __restrict__ y, const float* __restrict__ z,
    const int* __restrict__ idx, const float* __restrict__ g, const float* __restrict__ be,
    const float* __restrict__ rm, const float* __restrict__ rv,
    float* __restrict__ out, int co) {
    int n = blockIdx.x;   // global point id in [0, B*N)
    int o = threadIdx.x;
    int b = n >> 11;      // N = 2048
    __shared__ int sj[KK];
    if (o < KK) sj[o] = idx[(size_t)n * KK + o];
    __syncthreads();
    float yn = y[(size_t)n * co + o], zn = z[(size_t)n * co + o];
    float mx = -INFINITY, mn = INFINITY;
    #pragma unroll
    for (int j = 0; j < KK; ++j) {
        float v = y[((size_t)b * NN + sj[j]) * co + o];
        mx = fmaxf(mx, v);
        mn = fminf(mn, v);
    }
    float s = g[o] * rsqrtf(rv[o] + EPSF);
    float tt = be[o] - rm[o] * s;
    float ybest = (s >= 0.f) ? mx : mn;
    float h = fmaf(s, ybest - yn + zn, tt);
    out[(size_t)n * co + o] = (h >= 0.f) ? h : NEG_SLOPE * h;
}

// ---------------- global max over N of concat(x1..x4) ----------------
#define NSPLIT 32
__global__ void gmax_partial(const float* __restrict__ x1, const float* __restrict__ x2,
                             const float* __restrict__ x3, const float* __restrict__ x4,
                             float* __restrict__ part) {
    int ch = threadIdx.x;            // 0..511
    int split = blockIdx.x, b = blockIdx.y;
    int n0 = split * (NN / NSPLIT);
    float m = -INFINITY;
    for (int q = 0; q < NN / NSPLIT; ++q) {
        int n = b * NN + n0 + q;
        float v;
        if (ch < 64)       v = x1[(size_t)n * 64 + ch];
        else if (ch < 128) v = x2[(size_t)n * 64 + (ch - 64)];
        else if (ch < 256) v = x3[(size_t)n * 128 + (ch - 128)];
        else               v = x4[(size_t)n * 256 + (ch - 256)];
        m = fmaxf(m, v);
    }
    part[((size_t)split * BB + b) * 512 + ch] = m;
}

__global__ void gmax_final(const float* __restrict__ part, float* __restrict__ xg) {
    int ch = threadIdx.x, b = blockIdx.x;
    float m = -INFINITY;
    for (int s = 0; s < NSPLIT; ++s) m = fmaxf(m, part[((size_t)s * BB + b) * 512 + ch]);
    xg[(size_t)b * 512 + ch] = m;
}

// ---------------- final linear + BN + lrelu ----------------
__global__ void linear_kernel(const float* __restrict__ xg, const float* __restrict__ lw,
    const float* __restrict__ lb, const float* __restrict__ g5, const float* __restrict__ b5,
    const float* __restrict__ rm5, const float* __restrict__ rv5, float* __restrict__ out0) {
    int o = blockIdx.x * 256 + threadIdx.x;
    int b = blockIdx.y;
    __shared__ float xs[512];
    for (int l = threadIdx.x; l < 512; l += 256) xs[l] = xg[(size_t)b * 512 + l];
    __syncthreads();
    float acc = 0.f;
    const float* wr = lw + (size_t)o * 512;
    for (int c = 0; c < 512; ++c) acc = fmaf(xs[c], wr[c], acc);
    acc += lb[o];
    float s = g5[o] * rsqrtf(rv5[o] + EPSF);
    float h = fmaf(s, acc - rm5[o], b5[o]);
    out0[(size_t)b * 1024 + o] = (h >= 0.f) ? h : NEG_SLOPE * h;
}

// ---------------- x4 (B,N,256) -> out1 (B,256,N) ----------------
__global__ void transpose_kernel(const float* __restrict__ x4, float* __restrict__ out1) {
    __shared__ float tile[32][33];
    int b = blockIdx.z;
    int nb = blockIdx.x * 32, ob = blockIdx.y * 32;
    int tx = threadIdx.x, ty = threadIdx.y;  // (32, 8)
    #pragma unroll
    for (int r = 0; r < 4; ++r) {
        int o = ob + tx;
        int n = nb + ty + r * 8;
        tile[ty + r * 8][tx] = x4[((size_t)b * NN + n) * 256 + o];
    }
    __syncthreads();
    #pragma unroll
    for (int r = 0; r < 4; ++r) {
        int n = nb + tx;
        int o = ob + ty + r * 8;
        out1[((size_t)b * 256 + o) * NN + n] = tile[tx][ty + r * 8];
    }
}

extern "C" void kernel_launch(void* const* d_in, const int* in_sizes, int n_in,
                              void* d_out, int out_size, void* d_ws, size_t ws_size,
                              hipStream_t stream) {
    const float* x = (const float*)d_in[0];
    const float* lin_w = (const float*)d_in[21];
    const float* lin_b = (const float*)d_in[22];
    const float* g5 = (const float*)d_in[23];
    const float* b5 = (const float*)d_in[24];
    const float* rm5 = (const float*)d_in[25];
    const float* rv5 = (const float*)d_in[26];

    // ---- workspace bump allocation ----
    size_t off = 0;
    auto alloc = [&](size_t nbytes) {
        void* r = (char*)d_ws + off;
        off += (nbytes + 255) & ~(size_t)255;
        return r;
    };
    const size_t PTS = (size_t)BB * NN;
    float* xx   = (float*)alloc(PTS * 4);
    int*   idx  = (int*)  alloc(PTS * KK * 4);
    float* y    = (float*)alloc(PTS * 256 * 4);
    float* z    = (float*)alloc(PTS * 256 * 4);
    float* x1   = (float*)alloc(PTS * 64 * 4);
    float* x2   = (float*)alloc(PTS * 64 * 4);
    float* x3   = (float*)alloc(PTS * 128 * 4);
    float* x4   = (float*)alloc(PTS * 256 * 4);
    float* part = (float*)alloc((size_t)NSPLIT * BB * 512 * 4);
    float* xg   = (float*)alloc((size_t)BB * 512 * 4);
    size_t dist_full = (size_t)BB * NN * NN * 4;
    size_t dist_one  = (size_t)NN * NN * 4;
    bool full = (ws_size >= off + dist_full);
    float* dist = (float*)alloc(full ? dist_full : dist_one);

    const int CI[4] = {5, 64, 64, 128};
    const int CO[4] = {64, 64, 128, 256};
    const float* xin = x;
    float* xout[4] = {x1, x2, x3, x4};

    for (int l = 0; l < 4; ++l) {
        int C = CI[l], co = CO[l];
        const float* w  = (const float*)d_in[1 + l * 5 + 0];
        const float* g  = (const float*)d_in[1 + l * 5 + 1];
        const float* be = (const float*)d_in[1 + l * 5 + 2];
        const float* rm = (const float*)d_in[1 + l * 5 + 3];
        const float* rv = (const float*)d_in[1 + l * 5 + 4];

        xx_kernel<<<(BB * NN + 255) / 256, 256, 0, stream>>>(xin, xx, C);

        if (full) {
            dist_gemm_kernel<<<dim3(NN / 64, NN / 64, BB), 256, 0, stream>>>(xin, xx, dist, C, 0);
            topk_kernel<<<dim3(NN, BB), 64, 0, stream>>>(dist, idx, 0);
        } else {
            for (int b = 0; b < BB; ++b) {
                dist_gemm_kernel<<<dim3(NN / 64, NN / 64, 1), 256, 0, stream>>>(xin, xx, dist, C, b);
                topk_kernel<<<dim3(NN, 1), 64, 0, stream>>>(dist, idx, b);
            }
        }

        yz_kernel<<<(int)(PTS / TNPTS), co, TNPTS * C * 4, stream>>>(xin, w, y, z, C, co);
        edge_apply_kernel<<<(int)PTS, co, 0, stream>>>(y, z, idx, g, be, rm, rv, xout[l], co);
        xin = xout[l];
    }

    gmax_partial<<<dim3(NSPLIT, BB), 512, 0, stream>>>(x1, x2, x3, x4, part);
    gmax_final<<<BB, 512, 0, stream>>>(part, xg);
    linear_kernel<<<dim3(1024 / 256, BB), 256, 0, stream>>>(
        xg, lin_w, lin_b, g5, b5, rm5, rv5, (float*)d_out);
    transpose_kernel<<<dim3(NN / 32, 256 / 32, BB), dim3(32, 8), 0, stream>>>(
        x4, (float*)d_out + (size_t)BB * 1024);
}

// Round 2
// 907.576 us; speedup vs baseline: 1.4753x; 1.4753x over previous
//
#include <hip/hip_runtime.h>
#include <hip/hip_bf16.h>
#include <math.h>

#define BB 8
#define NN 2048
#define KK 10
#define EPSF 1e-5f
#define NEG_SLOPE 0.2f

// ---------------- xx[n] = sum_c x[n,c]^2 ----------------
__global__ void xx_kernel(const float* __restrict__ x, float* __restrict__ xx, int C) {
    int i = blockIdx.x * blockDim.x + threadIdx.x;
    if (i >= BB * NN) return;
    const float* row = x + (size_t)i * C;
    float s = 0.f;
    for (int c = 0; c < C; ++c) { float v = row[c]; s = fmaf(v, v, s); }
    xx[i] = s;
}

// ---------------- dist[b,i,j] = 2*dot(xi,xj) - xx[i] - xx[j] ----------------
// 64x64 tile, 4x4 per thread, k-chunk=16, k-major LDS for float4 reads.
// NOTE: numerics must stay bit-identical across rounds (neighbor ordering
// feeds everything downstream; absmax margin is thin). Do not reorder FMAs.
__global__ __launch_bounds__(256) void dist_gemm_kernel(
    const float* __restrict__ x, const float* __restrict__ xx,
    float* __restrict__ dist, int C, int b0) {
    int bz = blockIdx.z, b = b0 + bz;
    int i0 = blockIdx.y << 6, j0 = blockIdx.x << 6;
    const float* xb = x + (size_t)b * NN * C;
    __shared__ float As[16][68], Bs[16][68];
    int tid = threadIdx.x;
    int tx = tid & 15, ty = tid >> 4;
    float acc[4][4] = {};
    for (int k0 = 0; k0 < C; k0 += 16) {
        #pragma unroll
        for (int l = tid; l < 1024; l += 256) {
            int r = l >> 4, c = l & 15;
            int kc = k0 + c;
            As[c][r] = (kc < C) ? xb[(size_t)(i0 + r) * C + kc] : 0.f;
            Bs[c][r] = (kc < C) ? xb[(size_t)(j0 + r) * C + kc] : 0.f;
        }
        __syncthreads();
        #pragma unroll
        for (int kk = 0; kk < 16; ++kk) {
            float4 a4 = *(const float4*)&As[kk][ty << 2];
            float4 b4 = *(const float4*)&Bs[kk][tx << 2];
            float a[4] = {a4.x, a4.y, a4.z, a4.w};
            float bv[4] = {b4.x, b4.y, b4.z, b4.w};
            #pragma unroll
            for (int u = 0; u < 4; ++u)
                #pragma unroll
                for (int v = 0; v < 4; ++v)
                    acc[u][v] = fmaf(a[u], bv[v], acc[u][v]);
        }
        __syncthreads();
    }
    const float* xxb = xx + (size_t)b * NN;
    float xi[4], xj[4];
    #pragma unroll
    for (int u = 0; u < 4; ++u) xi[u] = xxb[i0 + (ty << 2) + u];
    #pragma unroll
    for (int v = 0; v < 4; ++v) xj[v] = xxb[j0 + (tx << 2) + v];
    float* db = dist + (size_t)bz * NN * NN;
    #pragma unroll
    for (int u = 0; u < 4; ++u) {
        int i = i0 + (ty << 2) + u;
        float4 o;
        o.x = 2.f * acc[u][0] - xi[u] - xj[0];
        o.y = 2.f * acc[u][1] - xi[u] - xj[1];
        o.z = 2.f * acc[u][2] - xi[u] - xj[2];
        o.w = 2.f * acc[u][3] - xi[u] - xj[3];
        *(float4*)&db[(size_t)i * NN + j0 + (tx << 2)] = o;
    }
}

// ---------------- top-10 per row, jax.lax.top_k semantics ----------------
// 256-thread block = 4 waves, one row per wave. Each lane holds 32 candidates
// (float4 loads; slot s -> j = 4*t + 256*(s>>2) + (s&3), ascending in s).
// Lazy top-2 per lane: full rescan only when a lane's two slots are consumed
// (expected ~0.3x per row after the initial pass). Extraction order is exactly
// (value desc, index asc) == jax.lax.top_k.
__global__ __launch_bounds__(256) void topk_kernel(
    const float* __restrict__ dist, int* __restrict__ idxout, int b0) {
    int wid = threadIdx.x >> 6;
    int t = threadIdx.x & 63;
    int i = (blockIdx.x << 2) + wid;
    int bz = blockIdx.y, b = b0 + bz;
    const float4* row4 = (const float4*)(dist + ((size_t)bz * NN + i) * NN);
    float v[32];
    #pragma unroll
    for (int q = 0; q < 8; ++q) {
        float4 f = row4[t + (q << 6)];
        v[q * 4 + 0] = f.x; v[q * 4 + 1] = f.y;
        v[q * 4 + 2] = f.z; v[q * 4 + 3] = f.w;
    }
    int jbase = t << 2;
    float m1 = -INFINITY, m2 = -INFINITY;
    int j1 = -1, j2 = -1;
    float lastv = INFINITY; int lastj = -1;
    int* out = idxout + ((size_t)b * NN + i) * KK;
    for (int r = 0; r < KK; ++r) {
        // refill lanes whose head is invalid (covers the initial pass at r=0)
        if (__any(j1 < 0)) {
            if (j1 < 0) {
                float nm1 = -INFINITY, nm2 = -INFINITY;
                int ns1 = -1, ns2 = -1;
                #pragma unroll
                for (int s = 0; s < 32; ++s) {
                    float vv = v[s];
                    int js = jbase + ((s >> 2) << 8) + (s & 3);
                    bool elig = (vv < lastv) || (vv == lastv && js > lastj);
                    bool b1 = elig && (vv > nm1);
                    bool b2 = elig && (vv > nm2);
                    nm2 = b1 ? nm1 : (b2 ? vv : nm2);
                    ns2 = b1 ? ns1 : (b2 ? js : ns2);
                    nm1 = b1 ? vv : nm1;
                    ns1 = b1 ? js : ns1;
                }
                m1 = nm1; j1 = ns1; m2 = nm2; j2 = ns2;
            }
        }
        float bv = m1; int bj = j1;
        #pragma unroll
        for (int s = 32; s; s >>= 1) {
            float ov = __shfl_xor(bv, s);
            int oj = __shfl_xor(bj, s);
            // unsigned j-compare: invalid (-1 = 0xFFFFFFFF) loses all ties
            if (ov > bv || (ov == bv && (unsigned)oj < (unsigned)bj)) { bv = ov; bj = oj; }
        }
        if (t == 0) out[r] = bj;
        if (j1 == bj) {  // owner (j unique) promotes; lazy refill later if needed
            lastv = m1; lastj = j1;
            m1 = m2; j1 = j2;
            m2 = -INFINITY; j2 = -1;
        }
    }
}

// ---------------- y = X*W1^T, z = X*W2^T (w = [W1 | W2], row o has 2C) ----------------
#define TNPTS 8
__global__ void yz_kernel(const float* __restrict__ x, const float* __restrict__ w,
                          float* __restrict__ y, float* __restrict__ z, int C, int co) {
    int o = threadIdx.x;
    int n0 = blockIdx.x * TNPTS;
    extern __shared__ float xs[];  // TNPTS * C
    for (int l = o; l < TNPTS * C; l += co) xs[l] = x[(size_t)n0 * C + l];
    __syncthreads();
    float ay[TNPTS] = {}, az[TNPTS] = {};
    const float* wy = w + (size_t)o * 2 * C;
    const float* wz = wy + C;
    for (int c = 0; c < C; ++c) {
        float a = wy[c], bq = wz[c];
        #pragma unroll
        for (int p = 0; p < TNPTS; ++p) {
            float xv = xs[p * C + c];
            ay[p] = fmaf(xv, a, ay[p]);
            az[p] = fmaf(xv, bq, az[p]);
        }
    }
    for (int p = 0; p < TNPTS; ++p) {
        y[(size_t)(n0 + p) * co + o] = ay[p];
        z[(size_t)(n0 + p) * co + o] = az[p];
    }
}

// ---------------- gather + max_k + BN + lrelu ----------------
__global__ void edge_apply_kernel(const float* __restrict__ y, const float* __restrict__ z,
    const int* __restrict__ idx, const float* __restrict__ g, const float* __restrict__ be,
    const float* __restrict__ rm, const float* __restrict__ rv,
    float* __restrict__ out, int co) {
    int n = blockIdx.x;   // global point id in [0, B*N)
    int o = threadIdx.x;
    int b = n >> 11;      // N = 2048
    __shared__ int sj[KK];
    if (o < KK) sj[o] = idx[(size_t)n * KK + o];
    __syncthreads();
    float yn = y[(size_t)n * co + o], zn = z[(size_t)n * co + o];
    float mx = -INFINITY, mn = INFINITY;
    #pragma unroll
    for (int j = 0; j < KK; ++j) {
        float v = y[((size_t)b * NN + sj[j]) * co + o];
        mx = fmaxf(mx, v);
        mn = fminf(mn, v);
    }
    float s = g[o] * rsqrtf(rv[o] + EPSF);
    float tt = be[o] - rm[o] * s;
    float ybest = (s >= 0.f) ? mx : mn;
    float h = fmaf(s, ybest - yn + zn, tt);
    out[(size_t)n * co + o] = (h >= 0.f) ? h : NEG_SLOPE * h;
}

// ---------------- global max over N of concat(x1..x4) ----------------
#define NSPLIT 32
__global__ void gmax_partial(const float* __restrict__ x1, const float* __restrict__ x2,
                             const float* __restrict__ x3, const float* __restrict__ x4,
                             float* __restrict__ part) {
    int ch = threadIdx.x;            // 0..511
    int split = blockIdx.x, b = blockIdx.y;
    int n0 = split * (NN / NSPLIT);
    float m = -INFINITY;
    for (int q = 0; q < NN / NSPLIT; ++q) {
        int n = b * NN + n0 + q;
        float v;
        if (ch < 64)       v = x1[(size_t)n * 64 + ch];
        else if (ch < 128) v = x2[(size_t)n * 64 + (ch - 64)];
        else if (ch < 256) v = x3[(size_t)n * 128 + (ch - 128)];
        else               v = x4[(size_t)n * 256 + (ch - 256)];
        m = fmaxf(m, v);
    }
    part[((size_t)split * BB + b) * 512 + ch] = m;
}

__global__ void gmax_final(const float* __restrict__ part, float* __restrict__ xg) {
    int ch = threadIdx.x, b = blockIdx.x;
    float m = -INFINITY;
    for (int s = 0; s < NSPLIT; ++s) m = fmaxf(m, part[((size_t)s * BB + b) * 512 + ch]);
    xg[(size_t)b * 512 + ch] = m;
}

// ---------------- final linear + BN + lrelu ----------------
__global__ void linear_kernel(const float* __restrict__ xg, const float* __restrict__ lw,
    const float* __restrict__ lb, const float* __restrict__ g5, const float* __restrict__ b5,
    const float* __restrict__ rm5, const float* __restrict__ rv5, float* __restrict__ out0) {
    int o = blockIdx.x * 256 + threadIdx.x;
    int b = blockIdx.y;
    __shared__ float xs[512];
    for (int l = threadIdx.x; l < 512; l += 256) xs[l] = xg[(size_t)b * 512 + l];
    __syncthreads();
    float acc = 0.f;
    const float* wr = lw + (size_t)o * 512;
    for (int c = 0; c < 512; ++c) acc = fmaf(xs[c], wr[c], acc);
    acc += lb[o];
    float s = g5[o] * rsqrtf(rv5[o] + EPSF);
    float h = fmaf(s, acc - rm5[o], b5[o]);
    out0[(size_t)b * 1024 + o] = (h >= 0.f) ? h : NEG_SLOPE * h;
}

// ---------------- x4 (B,N,256) -> out1 (B,256,N) ----------------
__global__ void transpose_kernel(const float* __restrict__ x4, float* __restrict__ out1) {
    __shared__ float tile[32][33];
    int b = blockIdx.z;
    int nb = blockIdx.x * 32, ob = blockIdx.y * 32;
    int tx = threadIdx.x, ty = threadIdx.y;  // (32, 8)
    #pragma unroll
    for (int r = 0; r < 4; ++r) {
        int o = ob + tx;
        int n = nb + ty + r * 8;
        tile[ty + r * 8][tx] = x4[((size_t)b * NN + n) * 256 + o];
    }
    __syncthreads();
    #pragma unroll
    for (int r = 0; r < 4; ++r) {
        int n = nb + tx;
        int o = ob + ty + r * 8;
        out1[((size_t)b * 256 + o) * NN + n] = tile[tx][ty + r * 8];
    }
}

extern "C" void kernel_launch(void* const* d_in, const int* in_sizes, int n_in,
                              void* d_out, int out_size, void* d_ws, size_t ws_size,
                              hipStream_t stream) {
    const float* x = (const float*)d_in[0];
    const float* lin_w = (const float*)d_in[21];
    const float* lin_b = (const float*)d_in[22];
    const float* g5 = (const float*)d_in[23];
    const float* b5 = (const float*)d_in[24];
    const float* rm5 = (const float*)d_in[25];
    const float* rv5 = (const float*)d_in[26];

    // ---- workspace bump allocation ----
    size_t off = 0;
    auto alloc = [&](size_t nbytes) {
        void* r = (char*)d_ws + off;
        off += (nbytes + 255) & ~(size_t)255;
        return r;
    };
    const size_t PTS = (size_t)BB * NN;
    float* xx   = (float*)alloc(PTS * 4);
    int*   idx  = (int*)  alloc(PTS * KK * 4);
    float* y    = (float*)alloc(PTS * 256 * 4);
    float* z    = (float*)alloc(PTS * 256 * 4);
    float* x1   = (float*)alloc(PTS * 64 * 4);
    float* x2   = (float*)alloc(PTS * 64 * 4);
    float* x3   = (float*)alloc(PTS * 128 * 4);
    float* x4   = (float*)alloc(PTS * 256 * 4);
    float* part = (float*)alloc((size_t)NSPLIT * BB * 512 * 4);
    float* xg   = (float*)alloc((size_t)BB * 512 * 4);
    size_t dist_full = (size_t)BB * NN * NN * 4;
    size_t dist_one  = (size_t)NN * NN * 4;
    bool full = (ws_size >= off + dist_full);
    float* dist = (float*)alloc(full ? dist_full : dist_one);

    const int CI[4] = {5, 64, 64, 128};
    const int CO[4] = {64, 64, 128, 256};
    const float* xin = x;
    float* xout[4] = {x1, x2, x3, x4};

    for (int l = 0; l < 4; ++l) {
        int C = CI[l], co = CO[l];
        const float* w  = (const float*)d_in[1 + l * 5 + 0];
        const float* g  = (const float*)d_in[1 + l * 5 + 1];
        const float* be = (const float*)d_in[1 + l * 5 + 2];
        const float* rm = (const float*)d_in[1 + l * 5 + 3];
        const float* rv = (const float*)d_in[1 + l * 5 + 4];

        xx_kernel<<<(BB * NN + 255) / 256, 256, 0, stream>>>(xin, xx, C);

        if (full) {
            dist_gemm_kernel<<<dim3(NN / 64, NN / 64, BB), 256, 0, stream>>>(xin, xx, dist, C, 0);
            topk_kernel<<<dim3(NN / 4, BB), 256, 0, stream>>>(dist, idx, 0);
        } else {
            for (int b = 0; b < BB; ++b) {
                dist_gemm_kernel<<<dim3(NN / 64, NN / 64, 1), 256, 0, stream>>>(xin, xx, dist, C, b);
                topk_kernel<<<dim3(NN / 4, 1), 256, 0, stream>>>(dist, idx, b);
            }
        }

        yz_kernel<<<(int)(PTS / TNPTS), co, TNPTS * C * 4, stream>>>(xin, w, y, z, C, co);
        edge_apply_kernel<<<(int)PTS, co, 0, stream>>>(y, z, idx, g, be, rm, rv, xout[l], co);
        xin = xout[l];
    }

    gmax_partial<<<dim3(NSPLIT, BB), 512, 0, stream>>>(x1, x2, x3, x4, part);
    gmax_final<<<BB, 512, 0, stream>>>(part, xg);
    linear_kernel<<<dim3(1024 / 256, BB), 256, 0, stream>>>(
        xg, lin_w, lin_b, g5, b5, rm5, rv5, (float*)d_out);
    transpose_kernel<<<dim3(NN / 32, 256 / 32, BB), dim3(32, 8), 0, stream>>>(
        x4, (float*)d_out + (size_t)BB * 1024);
}

// Round 3
// 804.659 us; speedup vs baseline: 1.6640x; 1.1279x over previous
//
#include <hip/hip_runtime.h>
#include <hip/hip_bf16.h>
#include <math.h>

#define BB 8
#define NN 2048
#define KK 10
#define EPSF 1e-5f
#define NEG_SLOPE 0.2f

// ---------------- xx[n] = sum_c x[n,c]^2 ----------------
__global__ void xx_kernel(const float* __restrict__ x, float* __restrict__ xx, int C) {
    int i = blockIdx.x * blockDim.x + threadIdx.x;
    if (i >= BB * NN) return;
    const float* row = x + (size_t)i * C;
    float s = 0.f;
    for (int c = 0; c < C; ++c) { float v = row[c]; s = fmaf(v, v, s); }
    xx[i] = s;
}

// ---------------- dist[b,i,j] = 2*dot(xi,xj) - xx[i] - xx[j] ----------------
// 64x64 tile, 4x4 per thread, k-chunk=16, k-major LDS for float4 reads.
// NOTE: numerics feed neighbor ordering; do not reorder FMAs.
__global__ __launch_bounds__(256) void dist_gemm_kernel(
    const float* __restrict__ x, const float* __restrict__ xx,
    float* __restrict__ dist, int C, int b0) {
    int bz = blockIdx.z, b = b0 + bz;
    int i0 = blockIdx.y << 6, j0 = blockIdx.x << 6;
    const float* xb = x + (size_t)b * NN * C;
    __shared__ float As[16][68], Bs[16][68];
    int tid = threadIdx.x;
    int tx = tid & 15, ty = tid >> 4;
    float acc[4][4] = {};
    for (int k0 = 0; k0 < C; k0 += 16) {
        #pragma unroll
        for (int l = tid; l < 1024; l += 256) {
            int r = l >> 4, c = l & 15;
            int kc = k0 + c;
            As[c][r] = (kc < C) ? xb[(size_t)(i0 + r) * C + kc] : 0.f;
            Bs[c][r] = (kc < C) ? xb[(size_t)(j0 + r) * C + kc] : 0.f;
        }
        __syncthreads();
        #pragma unroll
        for (int kk = 0; kk < 16; ++kk) {
            float4 a4 = *(const float4*)&As[kk][ty << 2];
            float4 b4 = *(const float4*)&Bs[kk][tx << 2];
            float a[4] = {a4.x, a4.y, a4.z, a4.w};
            float bv[4] = {b4.x, b4.y, b4.z, b4.w};
            #pragma unroll
            for (int u = 0; u < 4; ++u)
                #pragma unroll
                for (int v = 0; v < 4; ++v)
                    acc[u][v] = fmaf(a[u], bv[v], acc[u][v]);
        }
        __syncthreads();
    }
    const float* xxb = xx + (size_t)b * NN;
    float xi[4], xj[4];
    #pragma unroll
    for (int u = 0; u < 4; ++u) xi[u] = xxb[i0 + (ty << 2) + u];
    #pragma unroll
    for (int v = 0; v < 4; ++v) xj[v] = xxb[j0 + (tx << 2) + v];
    float* db = dist + (size_t)bz * NN * NN;
    #pragma unroll
    for (int u = 0; u < 4; ++u) {
        int i = i0 + (ty << 2) + u;
        float4 o;
        o.x = 2.f * acc[u][0] - xi[u] - xj[0];
        o.y = 2.f * acc[u][1] - xi[u] - xj[1];
        o.z = 2.f * acc[u][2] - xi[u] - xj[2];
        o.w = 2.f * acc[u][3] - xi[u] - xj[3];
        *(float4*)&db[(size_t)i * NN + j0 + (tx << 2)] = o;
    }
}

// ---------------- top-10 per row, jax.lax.top_k semantics ----------------
// 256-thread block = 4 waves, one row per wave. Lazy per-lane top-2 + butterfly.
__global__ __launch_bounds__(256) void topk_kernel(
    const float* __restrict__ dist, int* __restrict__ idxout, int b0) {
    int wid = threadIdx.x >> 6;
    int t = threadIdx.x & 63;
    int i = (blockIdx.x << 2) + wid;
    int bz = blockIdx.y, b = b0 + bz;
    const float4* row4 = (const float4*)(dist + ((size_t)bz * NN + i) * NN);
    float v[32];
    #pragma unroll
    for (int q = 0; q < 8; ++q) {
        float4 f = row4[t + (q << 6)];
        v[q * 4 + 0] = f.x; v[q * 4 + 1] = f.y;
        v[q * 4 + 2] = f.z; v[q * 4 + 3] = f.w;
    }
    int jbase = t << 2;
    float m1 = -INFINITY, m2 = -INFINITY;
    int j1 = -1, j2 = -1;
    float lastv = INFINITY; int lastj = -1;
    int* out = idxout + ((size_t)b * NN + i) * KK;
    for (int r = 0; r < KK; ++r) {
        if (__any(j1 < 0)) {
            if (j1 < 0) {
                float nm1 = -INFINITY, nm2 = -INFINITY;
                int ns1 = -1, ns2 = -1;
                #pragma unroll
                for (int s = 0; s < 32; ++s) {
                    float vv = v[s];
                    int js = jbase + ((s >> 2) << 8) + (s & 3);
                    bool elig = (vv < lastv) || (vv == lastv && js > lastj);
                    bool b1 = elig && (vv > nm1);
                    bool b2 = elig && (vv > nm2);
                    nm2 = b1 ? nm1 : (b2 ? vv : nm2);
                    ns2 = b1 ? ns1 : (b2 ? js : ns2);
                    nm1 = b1 ? vv : nm1;
                    ns1 = b1 ? js : ns1;
                }
                m1 = nm1; j1 = ns1; m2 = nm2; j2 = ns2;
            }
        }
        float bv = m1; int bj = j1;
        #pragma unroll
        for (int s = 32; s; s >>= 1) {
            float ov = __shfl_xor(bv, s);
            int oj = __shfl_xor(bj, s);
            if (ov > bv || (ov == bv && (unsigned)oj < (unsigned)bj)) { bv = ov; bj = oj; }
        }
        if (t == 0) out[r] = bj;
        if (j1 == bj) {
            lastv = m1; lastj = j1;
            m1 = m2; j1 = j2;
            m2 = -INFINITY; j2 = -1;
        }
    }
}

// ---------------- y,z = X*W1^T, X*W2^T as one tiled GEMM ----------------
// Combined N = 2*co (first co cols -> y via w[o][0:C], next co -> z via
// w[o][C:2C]); co % 64 == 0 so a 64-wide tile never straddles y/z.
// Accumulation order over c is ascending (identical to previous rounds ->
// y/z bit-identical). 64x64 tile, 4x4/thread, k-major LDS.
__global__ __launch_bounds__(256) void yz_gemm_kernel(
    const float* __restrict__ x, const float* __restrict__ w,
    float* __restrict__ y, float* __restrict__ z, int C, int co) {
    int n0 = blockIdx.y << 6;     // point tile
    int oc0 = blockIdx.x << 6;    // combined output-channel tile
    __shared__ float As[16][68], Bs[16][68];
    int tid = threadIdx.x;
    int tx = tid & 15, ty = tid >> 4;
    float acc[4][4] = {};
    for (int k0 = 0; k0 < C; k0 += 16) {
        #pragma unroll
        for (int l = tid; l < 1024; l += 256) {
            int r = l >> 4, c = l & 15;
            int kc = k0 + c;
            As[c][r] = (kc < C) ? x[(size_t)(n0 + r) * C + kc] : 0.f;
            float bvv = 0.f;
            if (kc < C) {
                int oc = oc0 + r;
                int wrow = (oc < co) ? oc : (oc - co);
                int wcol = (oc < co) ? kc : (C + kc);
                bvv = w[(size_t)wrow * 2 * C + wcol];
            }
            Bs[c][r] = bvv;
        }
        __syncthreads();
        #pragma unroll
        for (int kk = 0; kk < 16; ++kk) {
            float4 a4 = *(const float4*)&As[kk][ty << 2];
            float4 b4 = *(const float4*)&Bs[kk][tx << 2];
            float a[4] = {a4.x, a4.y, a4.z, a4.w};
            float bv[4] = {b4.x, b4.y, b4.z, b4.w};
            #pragma unroll
            for (int u = 0; u < 4; ++u)
                #pragma unroll
                for (int v = 0; v < 4; ++v)
                    acc[u][v] = fmaf(a[u], bv[v], acc[u][v]);
        }
        __syncthreads();
    }
    bool isY = (oc0 < co);
    float* dst = isY ? y : z;
    int c0 = isY ? oc0 : (oc0 - co);
    #pragma unroll
    for (int u = 0; u < 4; ++u) {
        int n = n0 + (ty << 2) + u;
        float4 o;
        o.x = acc[u][0]; o.y = acc[u][1]; o.z = acc[u][2]; o.w = acc[u][3];
        *(float4*)&dst[(size_t)n * co + c0 + (tx << 2)] = o;
    }
}

// ---------------- gather + max_k + BN + lrelu ----------------
__global__ void edge_apply_kernel(const float* __restrict__ y, const float* __restrict__ z,
    const int* __restrict__ idx, const float* __restrict__ g, const float* __restrict__ be,
    const float* __restrict__ rm, const float* __restrict__ rv,
    float* __restrict__ out, int co) {
    int n = blockIdx.x;   // global point id in [0, B*N)
    int o = threadIdx.x;
    int b = n >> 11;      // N = 2048
    __shared__ int sj[KK];
    if (o < KK) sj[o] = idx[(size_t)n * KK + o];
    __syncthreads();
    float yn = y[(size_t)n * co + o], zn = z[(size_t)n * co + o];
    float mx = -INFINITY, mn = INFINITY;
    #pragma unroll
    for (int j = 0; j < KK; ++j) {
        float v = y[((size_t)b * NN + sj[j]) * co + o];
        mx = fmaxf(mx, v);
        mn = fminf(mn, v);
    }
    float s = g[o] * rsqrtf(rv[o] + EPSF);
    float tt = be[o] - rm[o] * s;
    float ybest = (s >= 0.f) ? mx : mn;
    float h = fmaf(s, ybest - yn + zn, tt);
    out[(size_t)n * co + o] = (h >= 0.f) ? h : NEG_SLOPE * h;
}

// ---------------- global max over N of concat(x1..x4) ----------------
#define NSPLIT 32
__global__ void gmax_partial(const float* __restrict__ x1, const float* __restrict__ x2,
                             const float* __restrict__ x3, const float* __restrict__ x4,
                             float* __restrict__ part) {
    int ch = threadIdx.x;            // 0..511
    int split = blockIdx.x, b = blockIdx.y;
    int n0 = split * (NN / NSPLIT);
    float m = -INFINITY;
    for (int q = 0; q < NN / NSPLIT; ++q) {
        int n = b * NN + n0 + q;
        float v;
        if (ch < 64)       v = x1[(size_t)n * 64 + ch];
        else if (ch < 128) v = x2[(size_t)n * 64 + (ch - 64)];
        else if (ch < 256) v = x3[(size_t)n * 128 + (ch - 128)];
        else               v = x4[(size_t)n * 256 + (ch - 256)];
        m = fmaxf(m, v);
    }
    part[((size_t)split * BB + b) * 512 + ch] = m;
}

__global__ void gmax_final(const float* __restrict__ part, float* __restrict__ xg) {
    int ch = threadIdx.x, b = blockIdx.x;
    float m = -INFINITY;
    for (int s = 0; s < NSPLIT; ++s) m = fmaxf(m, part[((size_t)s * BB + b) * 512 + ch]);
    xg[(size_t)b * 512 + ch] = m;
}

// ---------------- final linear + BN + lrelu ----------------
__global__ void linear_kernel(const float* __restrict__ xg, const float* __restrict__ lw,
    const float* __restrict__ lb, const float* __restrict__ g5, const float* __restrict__ b5,
    const float* __restrict__ rm5, const float* __restrict__ rv5, float* __restrict__ out0) {
    int o = blockIdx.x * 256 + threadIdx.x;
    int b = blockIdx.y;
    __shared__ float xs[512];
    for (int l = threadIdx.x; l < 512; l += 256) xs[l] = xg[(size_t)b * 512 + l];
    __syncthreads();
    float acc = 0.f;
    const float* wr = lw + (size_t)o * 512;
    for (int c = 0; c < 512; ++c) acc = fmaf(xs[c], wr[c], acc);
    acc += lb[o];
    float s = g5[o] * rsqrtf(rv5[o] + EPSF);
    float h = fmaf(s, acc - rm5[o], b5[o]);
    out0[(size_t)b * 1024 + o] = (h >= 0.f) ? h : NEG_SLOPE * h;
}

// ---------------- x4 (B,N,256) -> out1 (B,256,N) ----------------
__global__ void transpose_kernel(const float* __restrict__ x4, float* __restrict__ out1) {
    __shared__ float tile[32][33];
    int b = blockIdx.z;
    int nb = blockIdx.x * 32, ob = blockIdx.y * 32;
    int tx = threadIdx.x, ty = threadIdx.y;  // (32, 8)
    #pragma unroll
    for (int r = 0; r < 4; ++r) {
        int o = ob + tx;
        int n = nb + ty + r * 8;
        tile[ty + r * 8][tx] = x4[((size_t)b * NN + n) * 256 + o];
    }
    __syncthreads();
    #pragma unroll
    for (int r = 0; r < 4; ++r) {
        int n = nb + tx;
        int o = ob + ty + r * 8;
        out1[((size_t)b * 256 + o) * NN + n] = tile[tx][ty + r * 8];
    }
}

extern "C" void kernel_launch(void* const* d_in, const int* in_sizes, int n_in,
                              void* d_out, int out_size, void* d_ws, size_t ws_size,
                              hipStream_t stream) {
    const float* x = (const float*)d_in[0];
    const float* lin_w = (const float*)d_in[21];
    const float* lin_b = (const float*)d_in[22];
    const float* g5 = (const float*)d_in[23];
    const float* b5 = (const float*)d_in[24];
    const float* rm5 = (const float*)d_in[25];
    const float* rv5 = (const float*)d_in[26];

    // ---- workspace bump allocation ----
    size_t off = 0;
    auto alloc = [&](size_t nbytes) {
        void* r = (char*)d_ws + off;
        off += (nbytes + 255) & ~(size_t)255;
        return r;
    };
    const size_t PTS = (size_t)BB * NN;
    float* xx   = (float*)alloc(PTS * 4);
    int*   idx  = (int*)  alloc(PTS * KK * 4);
    float* y    = (float*)alloc(PTS * 256 * 4);
    float* z    = (float*)alloc(PTS * 256 * 4);
    float* x1   = (float*)alloc(PTS * 64 * 4);
    float* x2   = (float*)alloc(PTS * 64 * 4);
    float* x3   = (float*)alloc(PTS * 128 * 4);
    float* x4   = (float*)alloc(PTS * 256 * 4);
    float* part = (float*)alloc((size_t)NSPLIT * BB * 512 * 4);
    float* xg   = (float*)alloc((size_t)BB * 512 * 4);
    size_t dist_full = (size_t)BB * NN * NN * 4;
    size_t dist_one  = (size_t)NN * NN * 4;
    bool full = (ws_size >= off + dist_full);
    float* dist = (float*)alloc(full ? dist_full : dist_one);

    const int CI[4] = {5, 64, 64, 128};
    const int CO[4] = {64, 64, 128, 256};
    const float* xin = x;
    float* xout[4] = {x1, x2, x3, x4};

    for (int l = 0; l < 4; ++l) {
        int C = CI[l], co = CO[l];
        const float* w  = (const float*)d_in[1 + l * 5 + 0];
        const float* g  = (const float*)d_in[1 + l * 5 + 1];
        const float* be = (const float*)d_in[1 + l * 5 + 2];
        const float* rm = (const float*)d_in[1 + l * 5 + 3];
        const float* rv = (const float*)d_in[1 + l * 5 + 4];

        xx_kernel<<<(BB * NN + 255) / 256, 256, 0, stream>>>(xin, xx, C);

        if (full) {
            dist_gemm_kernel<<<dim3(NN / 64, NN / 64, BB), 256, 0, stream>>>(xin, xx, dist, C, 0);
            topk_kernel<<<dim3(NN / 4, BB), 256, 0, stream>>>(dist, idx, 0);
        } else {
            for (int b = 0; b < BB; ++b) {
                dist_gemm_kernel<<<dim3(NN / 64, NN / 64, 1), 256, 0, stream>>>(xin, xx, dist, C, b);
                topk_kernel<<<dim3(NN / 4, 1), 256, 0, stream>>>(dist, idx, b);
            }
        }

        yz_gemm_kernel<<<dim3(2 * co / 64, (int)(PTS / 64)), 256, 0, stream>>>(
            xin, w, y, z, C, co);
        edge_apply_kernel<<<(int)PTS, co, 0, stream>>>(y, z, idx, g, be, rm, rv, xout[l], co);
        xin = xout[l];
    }

    gmax_partial<<<dim3(NSPLIT, BB), 512, 0, stream>>>(x1, x2, x3, x4, part);
    gmax_final<<<BB, 512, 0, stream>>>(part, xg);
    linear_kernel<<<dim3(1024 / 256, BB), 256, 0, stream>>>(
        xg, lin_w, lin_b, g5, b5, rm5, rv5, (float*)d_out);
    transpose_kernel<<<dim3(NN / 32, 256 / 32, BB), dim3(32, 8), 0, stream>>>(
        x4, (float*)d_out + (size_t)BB * 1024);
}